// Round 6
// baseline (9080.865 us; speedup 1.0000x reference)
//
#include <hip/hip_runtime.h>

// Problem constants (fixed by the reference)
#define NN 50000
#define TT 200
#define HH 128
#define EE 1600000

typedef _Float16 f16x8 __attribute__((ext_vector_type(8)));
typedef _Float16 f16x4 __attribute__((ext_vector_type(4)));
typedef __fp16 fp16x2 __attribute__((ext_vector_type(2)));
typedef float f32x4 __attribute__((ext_vector_type(4)));

__device__ __forceinline__ float sigf(float x) {
    return __builtin_amdgcn_rcpf(1.f + __expf(-x));
}
__device__ __forceinline__ float tanhf_(float x) {
    return 1.f - 2.f * __builtin_amdgcn_rcpf(__expf(2.f * x) + 1.f);
}
__device__ __forceinline__ f32x4 sig4(f32x4 x) {
    f32x4 r; r[0] = sigf(x[0]); r[1] = sigf(x[1]); r[2] = sigf(x[2]); r[3] = sigf(x[3]); return r;
}
__device__ __forceinline__ f32x4 tanh4(f32x4 x) {
    f32x4 r; r[0] = tanhf_(x[0]); r[1] = tanhf_(x[1]); r[2] = tanhf_(x[2]); r[3] = tanhf_(x[3]); return r;
}
__device__ __forceinline__ f32x4 splat4(float s) { f32x4 r = {s, s, s, s}; return r; }
__device__ __forceinline__ f16x4 pack4(f32x4 v) {
    struct P { fp16x2 lo, hi; } p;
    p.lo = __builtin_amdgcn_cvt_pkrtz(v[0], v[1]);
    p.hi = __builtin_amdgcn_cvt_pkrtz(v[2], v[3]);
    return __builtin_bit_cast(f16x4, p);
}

// ---------------------------------------------------------------------------
// Weight packing: W is (512,128) row-major (PyTorch [4H, H]).
// MFMA-16x16x32 A-fragment order (A rows = gatecols): tile jn (0..31), chunk kk:
// out[(jn*4+kk)*512 + L*8 + i] = W[jn*16 + (L&15)][kk*32 + (L>>4)*8 + i]  (f16)
// ---------------------------------------------------------------------------
__global__ void pack_w(const float* __restrict__ W, _Float16* __restrict__ out) {
    int tile = blockIdx.x;          // jn*4 + kk
    int jn = tile >> 2, kk = tile & 3;
    int L = threadIdx.x;            // 0..63
    int n = jn * 16 + (L & 15);
    int k0 = kk * 32 + (L >> 4) * 8;
    _Float16* dst = out + (size_t)tile * 512 + L * 8;
#pragma unroll
    for (int i = 0; i < 8; ++i) dst[i] = (_Float16)W[n * 128 + k0 + i];
}

__global__ void bias_prep(const float* __restrict__ bih0, const float* __restrict__ bhh0,
                          const float* __restrict__ bih1, const float* __restrict__ bhh1,
                          const float* __restrict__ wih0,
                          float* __restrict__ b0g, float* __restrict__ b1g, float* __restrict__ wxg) {
    int i = blockIdx.x * 256 + threadIdx.x;
    if (i < 512) {
        b0g[i] = bih0[i] + bhh0[i];
        b1g[i] = bih1[i] + bhh1[i];
        wxg[i] = wih0[i];
    }
}

// lightcurve [N][T] -> xT [T][N]
__global__ void transpose_lc(const float* __restrict__ lc, float* __restrict__ xT) {
    __shared__ float tile[32][33];
    int tx = threadIdx.x, ty = threadIdx.y;    // 32 x 8
    int n0 = blockIdx.y * 32, t0 = blockIdx.x * 32;
#pragma unroll
    for (int i = 0; i < 32; i += 8) {
        int n = n0 + ty + i, t = t0 + tx;
        if (n < NN && t < TT) tile[ty + i][tx] = lc[(size_t)n * TT + t];
    }
    __syncthreads();
#pragma unroll
    for (int i = 0; i < 32; i += 8) {
        int t = t0 + ty + i, n = n0 + tx;
        if (n < NN && t < TT) xT[(size_t)t * NN + n] = tile[tx][ty + i];
    }
}

// ---------------------------------------------------------------------------
// Fused 2-layer LSTM. Block = 512 threads (8 waves), 32 nodes, 200 steps.
// MFMA orientation: A = weights (rows = gatecols), B = h (cols = nodes) ->
// D[gatecol][node]: lane holds 4 CONSECUTIVE hidden cols (j0..j0+3) for one
// node -> vector biases, b64 h-writes, f32x4 epilogue, float4 final store.
// Pipeline: one barrier per step — interval k computes L1(k) then L0(k+1),
// reading buffers [rp], writing [wp] (double-buffered h1/h2 in LDS f16).
// ---------------------------------------------------------------------------

#define MFMA16(A, B, C) __builtin_amdgcn_mfma_f32_16x16x32_f16((A), (B), (C), 0, 0, 0)

// One 32-wide K-chunk: 4 weight A-frags (gates, global), 2 h B-frags (LDS), 8 MFMAs
#define MMCW(WB, HR, KK) {                                                      \
    const _Float16* wb_ = (WB) + (size_t)(KK) * 512 + lane * 8;                 \
    f16x8 wI_ = *reinterpret_cast<const f16x8*>(wb_ + (size_t)(0 * 8 + wj) * 2048); \
    f16x8 wF_ = *reinterpret_cast<const f16x8*>(wb_ + (size_t)(1 * 8 + wj) * 2048); \
    f16x8 wG_ = *reinterpret_cast<const f16x8*>(wb_ + (size_t)(2 * 8 + wj) * 2048); \
    f16x8 wO_ = *reinterpret_cast<const f16x8*>(wb_ + (size_t)(3 * 8 + wj) * 2048); \
    f16x8 h0_ = *reinterpret_cast<const f16x8*>(&(HR)[col][(KK) * 32 + quad * 8]);      \
    f16x8 h1_ = *reinterpret_cast<const f16x8*>(&(HR)[16 + col][(KK) * 32 + quad * 8]); \
    aI0 = MFMA16(wI_, h0_, aI0); aI1 = MFMA16(wI_, h1_, aI1);                   \
    aF0 = MFMA16(wF_, h0_, aF0); aF1 = MFMA16(wF_, h1_, aF1);                   \
    aG0 = MFMA16(wG_, h0_, aG0); aG1 = MFMA16(wG_, h1_, aG1);                   \
    aO0 = MFMA16(wO_, h0_, aO0); aO1 = MFMA16(wO_, h1_, aO1);                   \
}

// Layer-0 epilogue for node-tile NT (x terms; XB = xs parity buffer)
#define EPIL0(NT, C, HV, AI, AF, AG, AO, XB) {                                  \
    f32x4 bI_ = *reinterpret_cast<const f32x4*>(&b0s[j0]);                      \
    f32x4 bF_ = *reinterpret_cast<const f32x4*>(&b0s[128 + j0]);                \
    f32x4 bG_ = *reinterpret_cast<const f32x4*>(&b0s[256 + j0]);                \
    f32x4 bO_ = *reinterpret_cast<const f32x4*>(&b0s[384 + j0]);                \
    f32x4 wIv_ = *reinterpret_cast<const f32x4*>(&wxs[j0]);                     \
    f32x4 wFv_ = *reinterpret_cast<const f32x4*>(&wxs[128 + j0]);               \
    f32x4 wGv_ = *reinterpret_cast<const f32x4*>(&wxs[256 + j0]);               \
    f32x4 wOv_ = *reinterpret_cast<const f32x4*>(&wxs[384 + j0]);               \
    f32x4 xv_ = splat4(xs[XB][(NT) * 16 + col]);                                \
    f32x4 gi_ = AI + bI_ + xv_ * wIv_;                                          \
    f32x4 gf_ = AF + bF_ + xv_ * wFv_;                                          \
    f32x4 gg_ = AG + bG_ + xv_ * wGv_;                                          \
    f32x4 go_ = AO + bO_ + xv_ * wOv_;                                          \
    C = sig4(gf_) * C + sig4(gi_) * tanh4(gg_);                                 \
    HV = sig4(go_) * tanh4(C);                                                  \
}

// Layer-1 epilogue (no x terms)
#define EPIL1(NT, C, HV, AI, AF, AG, AO) {                                      \
    f32x4 bI_ = *reinterpret_cast<const f32x4*>(&b1s[j0]);                      \
    f32x4 bF_ = *reinterpret_cast<const f32x4*>(&b1s[128 + j0]);                \
    f32x4 bG_ = *reinterpret_cast<const f32x4*>(&b1s[256 + j0]);                \
    f32x4 bO_ = *reinterpret_cast<const f32x4*>(&b1s[384 + j0]);                \
    f32x4 gi_ = AI + bI_;                                                       \
    f32x4 gf_ = AF + bF_;                                                       \
    f32x4 gg_ = AG + bG_;                                                       \
    f32x4 go_ = AO + bO_;                                                       \
    C = sig4(gf_) * C + sig4(gi_) * tanh4(gg_);                                 \
    HV = sig4(go_) * tanh4(C);                                                  \
}

// Pack 4 consecutive hidden cols to f16 and write as one b64
#define WRHV(DST, NT, HV) \
    *reinterpret_cast<f16x4*>(&(DST)[(NT) * 16 + col][j0]) = pack4(HV);

__global__ __launch_bounds__(512, 2) void lstm_kernel(
    const float* __restrict__ xT,
    const _Float16* __restrict__ w0p,
    const _Float16* __restrict__ w1ip,
    const _Float16* __restrict__ w1hp,
    const float* __restrict__ b0g, const float* __restrict__ b1g,
    const float* __restrict__ wxg,
    float* __restrict__ h2out) {
    __shared__ _Float16 h1s[2][32][136];   // [buf][node][feature], f16
    __shared__ _Float16 h2s[2][32][136];
    __shared__ __align__(16) float xs[2][32];
    __shared__ __align__(16) float b0s[512], b1s[512], wxs[512];

    const int tid = threadIdx.x;
    const int w = tid >> 6;                            // wave id 0..7
    const int wj = __builtin_amdgcn_readfirstlane(w);  // wave-uniform hidden-tile
    const int lane = tid & 63;
    const int col = lane & 15;
    const int quad = lane >> 4;
    const int n0 = blockIdx.x * 32;
    const int j0 = wj * 16 + quad * 4;                 // lane's hidden-col base

    // zero h2s[1] (h2(-1)); h1s[1] fully written by prologue; pads never read
    for (int i = tid; i < 32 * 136; i += 512) (&h2s[1][0][0])[i] = (_Float16)0;
    if (tid < 512) { b0s[tid] = b0g[tid]; b1s[tid] = b1g[tid]; wxs[tid] = wxg[tid]; }
    if (tid < 32) {
        int n = n0 + tid;
        xs[0][tid] = (n < NN) ? xT[n] : 0.f;                 // x(0)
        xs[1][tid] = (n < NN) ? xT[(size_t)NN + n] : 0.f;    // x(1)
    }

    // persistent cell state: (node-tile, 4 hidden cols) per lane
    f32x4 c1_0 = {}, c1_1 = {}, c2_0 = {}, c2_1 = {};

    __syncthreads();

    // prologue: L0(0) with h1(-1)=0 -> pure bias+x epilogue, write h1(0)->buf 1
    {
        f32x4 z = {};
        f32x4 h1v0, h1v1;
        EPIL0(0, c1_0, h1v0, z, z, z, z, 0)
        EPIL0(1, c1_1, h1v1, z, z, z, z, 0)
        WRHV(h1s[1], 0, h1v0)
        WRHV(h1s[1], 1, h1v1)
    }
    __syncthreads();

    // intervals k=0..198: L1(k) + L0(k+1); read bufs [rp], write [wp]
#pragma unroll 1
    for (int k = 0; k < TT - 1; ++k) {
        const int wp = k & 1;
        const int rp = wp ^ 1;
        _Float16 (*h1r)[136] = h1s[rp];
        _Float16 (*h2r)[136] = h2s[rp];
        _Float16 (*h1w)[136] = h1s[wp];
        _Float16 (*h2w)[136] = h2s[wp];
        {   // L1(k): h1(k) @ w1i + h2(k-1) @ w1h
            f32x4 aI0 = {}, aI1 = {}, aF0 = {}, aF1 = {};
            f32x4 aG0 = {}, aG1 = {}, aO0 = {}, aO1 = {};
            MMCW(w1ip, h1r, 0) MMCW(w1ip, h1r, 1) MMCW(w1ip, h1r, 2) MMCW(w1ip, h1r, 3)
            MMCW(w1hp, h2r, 0) MMCW(w1hp, h2r, 1) MMCW(w1hp, h2r, 2) MMCW(w1hp, h2r, 3)
            f32x4 h2v0, h2v1;
            EPIL1(0, c2_0, h2v0, aI0, aF0, aG0, aO0)
            EPIL1(1, c2_1, h2v1, aI1, aF1, aG1, aO1)
            WRHV(h2w, 0, h2v0)
            WRHV(h2w, 1, h2v1)
        }
        if (tid < 32) {   // prefetch x(k+2) into the buffer read next interval
            int n_ = n0 + tid;
            float xv = 0.f;
            if (k + 2 < TT && n_ < NN) xv = xT[(size_t)(k + 2) * NN + n_];
            xs[wp][tid] = xv;
        }
        {   // L0(k+1): h1(k) @ w0 + x(k+1)*wx
            f32x4 aI0 = {}, aI1 = {}, aF0 = {}, aF1 = {};
            f32x4 aG0 = {}, aG1 = {}, aO0 = {}, aO1 = {};
            MMCW(w0p, h1r, 0) MMCW(w0p, h1r, 1) MMCW(w0p, h1r, 2) MMCW(w0p, h1r, 3)
            f32x4 h1v0, h1v1;
            EPIL0(0, c1_0, h1v0, aI0, aF0, aG0, aO0, rp)
            EPIL0(1, c1_1, h1v1, aI1, aF1, aG1, aO1, rp)
            WRHV(h1w, 0, h1v0)
            WRHV(h1w, 1, h1v1)
        }
        __syncthreads();
    }

    // final L1(199): read bufs [0] (written at k=198), store h2 straight to global
    {
        _Float16 (*h1r)[136] = h1s[0];
        _Float16 (*h2r)[136] = h2s[0];
        f32x4 aI0 = {}, aI1 = {}, aF0 = {}, aF1 = {};
        f32x4 aG0 = {}, aG1 = {}, aO0 = {}, aO1 = {};
        MMCW(w1ip, h1r, 0) MMCW(w1ip, h1r, 1) MMCW(w1ip, h1r, 2) MMCW(w1ip, h1r, 3)
        MMCW(w1hp, h2r, 0) MMCW(w1hp, h2r, 1) MMCW(w1hp, h2r, 2) MMCW(w1hp, h2r, 3)
        f32x4 h2v0, h2v1;
        EPIL1(0, c2_0, h2v0, aI0, aF0, aG0, aO0)
        EPIL1(1, c2_1, h2v1, aI1, aF1, aG1, aO1)
        int nA = n0 + col, nB = n0 + 16 + col;
        if (nA < NN) *reinterpret_cast<f32x4*>(&h2out[(size_t)nA * HH + j0]) = h2v0;
        if (nB < NN) *reinterpret_cast<f32x4*>(&h2out[(size_t)nB * HH + j0]) = h2v1;
    }
}

// ---------------------------------------------------------------------------
// GCN pieces (fp32)
// ---------------------------------------------------------------------------
__global__ void deg_init(float* __restrict__ deg) {
    int i = blockIdx.x * 256 + threadIdx.x;
    if (i < NN) deg[i] = 1.f;   // self loop
}
__global__ void deg_edges(const int* __restrict__ ei, float* __restrict__ deg) {
    int e = blockIdx.x * 256 + threadIdx.x;
    if (e < EE) unsafeAtomicAdd(&deg[ei[EE + e]], 1.f);   // col = target
}
__global__ void dinv_k(const float* __restrict__ deg, float* __restrict__ dinv) {
    int i = blockIdx.x * 256 + threadIdx.x;
    if (i < NN) dinv[i] = rsqrtf(fmaxf(deg[i], 1.f));
}

// exclusive scan of per-node in-edge counts (deg-1) -> off[0..NN]
__global__ void scan_off(const float* __restrict__ deg, int* __restrict__ off) {
    __shared__ int sp[256];
    const int tid = threadIdx.x;
    const int chunk = (NN + 255) / 256;
    const int i0 = tid * chunk;
    int s = 0;
    for (int i = 0; i < chunk; ++i) {
        int idx = i0 + i;
        if (idx < NN) s += (int)deg[idx] - 1;
    }
    sp[tid] = s;
    __syncthreads();
    for (int o = 1; o < 256; o <<= 1) {
        int v = (tid >= o) ? sp[tid - o] : 0;
        __syncthreads();
        sp[tid] += v;
        __syncthreads();
    }
    int run = sp[tid] - s;
    for (int i = 0; i < chunk; ++i) {
        int idx = i0 + i;
        if (idx < NN) { off[idx] = run; run += (int)deg[idx] - 1; }
    }
    if (tid == 255) off[NN] = sp[255];
}

__global__ void csr_fill(const int* __restrict__ ei, const float* __restrict__ dinv,
                         const int* __restrict__ off, int* __restrict__ cur,
                         int* __restrict__ crow, float* __restrict__ cw) {
    int e = blockIdx.x * 256 + threadIdx.x;
    if (e >= EE) return;
    int r = ei[e], c = ei[EE + e];
    int p = atomicAdd(&cur[c], 1);
    int idx = off[c] + p;
    crow[idx] = r;
    cw[idx] = dinv[r] * dinv[c];
}

// hw = h @ Wg   ([N,128] x [128,128]); 32 nodes per block
__global__ void gcn_gemm(const float* __restrict__ h, const float* __restrict__ Wg,
                         float* __restrict__ hw) {
    __shared__ float hsT[128][36];
    int tid = threadIdx.x;
    int n0 = blockIdx.x * 32;
#pragma unroll
    for (int c = 0; c < 16; ++c) {
        int lin = c * 256 + tid;
        int m = lin >> 7, k = lin & 127;
        int n = n0 + m;
        hsT[k][m] = (n < NN) ? h[(size_t)n * HH + k] : 0.f;
    }
    __syncthreads();
    int j = tid & 127, p = tid >> 7;
    float acc[16];
#pragma unroll
    for (int m = 0; m < 16; ++m) acc[m] = 0.f;
    for (int k = 0; k < 128; ++k) {
        float wg = Wg[k * 128 + j];
        const float4* hp = reinterpret_cast<const float4*>(&hsT[k][p * 16]);
        float4 a = hp[0], b = hp[1], c = hp[2], d = hp[3];
        acc[0]  += a.x * wg; acc[1]  += a.y * wg; acc[2]  += a.z * wg; acc[3]  += a.w * wg;
        acc[4]  += b.x * wg; acc[5]  += b.y * wg; acc[6]  += b.z * wg; acc[7]  += b.w * wg;
        acc[8]  += c.x * wg; acc[9]  += c.y * wg; acc[10] += c.z * wg; acc[11] += c.w * wg;
        acc[12] += d.x * wg; acc[13] += d.y * wg; acc[14] += d.z * wg; acc[15] += d.w * wg;
    }
#pragma unroll
    for (int m = 0; m < 16; ++m) {
        int n = n0 + p * 16 + m;
        if (n < NN) hw[(size_t)n * HH + j] = acc[m];
    }
}

// Fused: self-loop + CSR gather + bias + LayerNorm + ReLU + residual
__global__ __launch_bounds__(256) void gcn_agg(
    const float* __restrict__ hw, const int* __restrict__ off,
    const int* __restrict__ crow, const float* __restrict__ cw,
    const float* __restrict__ dinv, const float* __restrict__ bg,
    const float* __restrict__ gamma, const float* __restrict__ beta,
    float* __restrict__ h) {
    __shared__ float xch[4][2];
    const int tid = threadIdx.x;
    const int half = tid >> 7;
    const int f = tid & 127;
    const int v = blockIdx.x * 2 + half;
    const float d = dinv[v];
    float acc = bg[f] + d * d * hw[v * HH + f];
    const int s1 = off[v + 1];
    for (int s = off[v]; s < s1; ++s) {
        int r = crow[s];
        float wv = cw[s];
        acc = fmaf(wv, hw[r * HH + f], acc);
    }
    float sum = acc, sq = acc * acc;
#pragma unroll
    for (int o = 32; o; o >>= 1) { sum += __shfl_xor(sum, o); sq += __shfl_xor(sq, o); }
    int wid = tid >> 6;
    if ((tid & 63) == 0) { xch[wid][0] = sum; xch[wid][1] = sq; }
    __syncthreads();
    sum += xch[wid ^ 1][0]; sq += xch[wid ^ 1][1];
    float mu = sum * (1.f / 128.f);
    float var = sq * (1.f / 128.f) - mu * mu;
    float rn = rsqrtf(var + 1e-5f);
    float o = (acc - mu) * rn * gamma[f] + beta[f];
    h[v * HH + f] = fmaxf(o, 0.f) + h[v * HH + f];
}

__global__ void pool_k(const float* __restrict__ h, float* __restrict__ pooled) {
    int j = threadIdx.x & 127, p = threadIdx.x >> 7;
    float s = 0.f;
    for (int n = blockIdx.x * 2 + p; n < NN; n += 512) s += h[(size_t)n * HH + j];
    unsafeAtomicAdd(&pooled[j], s);
}

__global__ void final_k(const float* __restrict__ pooled, const float* __restrict__ Wout,
                        const float* __restrict__ bout, float* __restrict__ out) {
    int lane = threadIdx.x;
    float s = pooled[lane] * Wout[lane] + pooled[lane + 64] * Wout[lane + 64];
#pragma unroll
    for (int o = 32; o; o >>= 1) s += __shfl_xor(s, o);
    if (lane == 0) out[0] = s * (1.f / (float)NN) + bout[0];
}

// ---------------------------------------------------------------------------
extern "C" void kernel_launch(void* const* d_in, const int* in_sizes, int n_in,
                              void* d_out, int out_size, void* d_ws, size_t ws_size,
                              hipStream_t stream) {
    const float* lc   = (const float*)d_in[0];
    const int*   ei   = (const int*)d_in[1];
    const float* Wih0 = (const float*)d_in[2];
    const float* Whh0 = (const float*)d_in[3];
    const float* bih0 = (const float*)d_in[4];
    const float* bhh0 = (const float*)d_in[5];
    const float* Wih1 = (const float*)d_in[6];
    const float* Whh1 = (const float*)d_in[7];
    const float* bih1 = (const float*)d_in[8];
    const float* bhh1 = (const float*)d_in[9];
    const float* Wout = (const float*)d_in[22];
    const float* bout = (const float*)d_in[23];
    float* out = (float*)d_out;

    float* ws   = (float*)d_ws;
    float* h    = ws;
    float* hw   = ws + 6400000;
    float* xT   = ws + 6400000;                    // aliases hw+CSR region pre-LSTM
    int*   off  = (int*)(ws + 12800000);
    int*   cur  = off + 50048;
    int*   crow = cur + 50048;
    float* cw   = (float*)(crow + EE);
    float* P      = ws + 16400064;
    float* deg    = P;
    float* dinv   = deg + 50000;
    float* b0g    = dinv + 50000;
    float* b1g    = b0g + 512;
    float* wxg    = b1g + 512;
    float* pooled = wxg + 512;
    _Float16* w0p  = (_Float16*)(pooled + 128);
    _Float16* w1ip = w0p + 65536;
    _Float16* w1hp = w1ip + 65536;

    pack_w<<<128, 64, 0, stream>>>(Whh0, w0p);
    pack_w<<<128, 64, 0, stream>>>(Wih1, w1ip);
    pack_w<<<128, 64, 0, stream>>>(Whh1, w1hp);
    bias_prep<<<2, 256, 0, stream>>>(bih0, bhh0, bih1, bhh1, Wih0, b0g, b1g, wxg);
    {
        dim3 g((TT + 31) / 32, (NN + 31) / 32), b(32, 8);
        transpose_lc<<<g, b, 0, stream>>>(lc, xT);
    }
    deg_init<<<(NN + 255) / 256, 256, 0, stream>>>(deg);
    deg_edges<<<(EE + 255) / 256, 256, 0, stream>>>(ei, deg);
    dinv_k<<<(NN + 255) / 256, 256, 0, stream>>>(deg, dinv);

    lstm_kernel<<<(NN + 31) / 32, 512, 0, stream>>>(xT, w0p, w1ip, w1hp, b0g, b1g, wxg, h);

    hipMemsetAsync(cur, 0, 50000 * sizeof(int), stream);
    scan_off<<<1, 256, 0, stream>>>(deg, off);
    csr_fill<<<(EE + 255) / 256, 256, 0, stream>>>(ei, dinv, off, cur, crow, cw);

    for (int l = 0; l < 3; ++l) {
        const float* Wg = (const float*)d_in[10 + 4 * l];
        const float* bg = (const float*)d_in[11 + 4 * l];
        const float* gm = (const float*)d_in[12 + 4 * l];
        const float* bt = (const float*)d_in[13 + 4 * l];
        gcn_gemm<<<(NN + 31) / 32, 256, 0, stream>>>(h, Wg, hw);
        gcn_agg<<<NN / 2, 256, 0, stream>>>(hw, off, crow, cw, dinv, bg, gm, bt, h);
    }

    hipMemsetAsync(pooled, 0, HH * sizeof(float), stream);
    pool_k<<<256, 256, 0, stream>>>(h, pooled);
    final_k<<<1, 64, 0, stream>>>(pooled, Wout, bout, out);
}